// Round 7
// baseline (940.364 us; speedup 1.0000x reference)
//
#include <hip/hip_runtime.h>
#include <cstdint>

#define U64 unsigned long long

static constexpr int H = 38, W = 50, P = 1900;        // feature map
static constexpr int CIN = 2048, CMID = 256;
static constexpr int NA = 9, NBOX = 17100;            // 1900*9
static constexpr int HP = 40, WP = 52, QP = HP * WP;  // padded positions (2080)
static constexpr int TPITCH = 2084;                   // in_tT row pitch (floats), mult of 4
static constexpr int KS = 7;                          // split-K over cin
static constexpr int NW = 268;                        // u64 words covering NBOX bits
static constexpr int MSTRIDE = 272;                   // mask row stride (words)
static constexpr float NMS_T = 0.5f;
static constexpr int QTILE = 256;

// ---------------- ws layout (bytes) ----------------
static constexpr size_t SZ_INT  = (size_t)CIN * TPITCH * 4;   // 17,072,128
static constexpr size_t SZ_WT   = (size_t)9 * CIN * CMID * 4; // 18,874,368
static constexpr size_t SZ_PART = (size_t)KS * P * CMID * 4;  // 13,619,200
static constexpr size_t OFF_INT  = 0;
static constexpr size_t OFF_WT   = OFF_INT + SZ_INT;
static constexpr size_t OFF_PART = OFF_WT + SZ_WT;
static constexpr size_t REGA     = OFF_PART + SZ_PART;        // 49,565,696
static constexpr size_t OFF_MASK = 0;                          // mask [NBOX][MSTRIDE] overlays region A (37.2 MB)
static constexpr size_t OFF_MID  = REGA;
static constexpr size_t OFF_FG   = OFF_MID + 1945600;
static constexpr size_t OFF_BOX  = OFF_FG + 68608;
static constexpr size_t OFF_SBOX = OFF_BOX + 273664;
static constexpr size_t OFF_SAREA= OFF_SBOX + 273664;
static constexpr size_t OFF_CNT  = OFF_SAREA + 68608;
static constexpr size_t WS_NEED  = OFF_CNT + 68608;            // ~52.26 MB

__device__ __forceinline__ U64 rdlane64(U64 v, int l) {
    unsigned lo = (unsigned)__builtin_amdgcn_readlane((int)(unsigned)(v & 0xffffffffull), l);
    unsigned hi = (unsigned)__builtin_amdgcn_readlane((int)(unsigned)(v >> 32), l);
    return ((U64)hi << 32) | (U64)lo;
}

// ---------------- kernels ----------------

__global__ __launch_bounds__(256) void k_sentinel(float* out, int n) {
    int i = blockIdx.x * 256 + threadIdx.x;
    if (i < n) out[i] = 1.2345678e8f;
}

// feature_map [CIN][H][W] -> in_tT [CIN][TPITCH] (padded image rows; memset first)
__global__ __launch_bounds__(256) void k_in_t(const float* __restrict__ fm, float* __restrict__ in_tT) {
    int idx = blockIdx.x * 256 + threadIdx.x;
    if (idx >= CIN * (H * W)) return;
    int ci = idx / (H * W), hw = idx - ci * (H * W);
    int h = hw / W, w = hw - h * W;
    in_tT[(size_t)ci * TPITCH + (h + 1) * WP + 1 + w] = fm[idx];
}

// conv_w [CMID][CIN][3][3] -> w2 [y(8)][sub(4)][ci(2048)][k(9)][c(8)]
__global__ __launch_bounds__(256) void k_w_t(const float* __restrict__ cw, float* __restrict__ w2) {
    int idx = blockIdx.x * 256 + threadIdx.x;
    if (idx >= CMID * CIN * 9) return;
    int co = idx / (CIN * 9);
    int rem = idx - co * (CIN * 9);
    int ci = rem / 9, k = rem - ci * 9;
    w2[((size_t)(co >> 3) * CIN + ci) * 72 + k * 8 + (co & 7)] = cw[idx];
}

// 3x3 conv, split-K. grid 504 = 9 qtiles x 8 cout-groups x 7 z (XCD-swizzled).
__global__ __launch_bounds__(256, 2) void k_conv(const float* __restrict__ in_tT,
                                                 const float* __restrict__ w2,
                                                 float* __restrict__ partial) {
    __shared__ float4 s_in4[16 * 104];   // 16 ci x 104 skewed quads (26.6 KB)
    int t = threadIdx.x;
    int lane = t & 63;
    int sub = __builtin_amdgcn_readfirstlane(t >> 6);   // wave-uniform SGPR

    int raw = blockIdx.x;
    int xcd = raw & 7, i0 = raw >> 3;
    int L = xcd * 63 + i0;          // 504 = 8*63, bijective
    int z = L / 72;
    int r0 = L - z * 72;
    int bx = r0 % 9, by = r0 / 9;
    int q0 = bx * QTILE;
    int cout0 = by * 32;
    int cin0 = (z <= 1) ? 304 * z : 608 + 288 * (z - 2);   // 304,304,288x5
    int cin1 = cin0 + ((z <= 1) ? 304 : 288);

    float acc[4][8];
#pragma unroll
    for (int j = 0; j < 4; ++j)
#pragma unroll
        for (int c = 0; c < 8; ++c) acc[j][c] = 0.f;

    const float* wbase = w2 + (size_t)(by * 4 + sub) * CIN * 72;

    for (int c0 = cin0; c0 < cin1; c0 += 16) {
        for (int idx = t; idx < 16 * 92; idx += 256) {
            int r = idx / 92, j = idx - r * 92;
            int qf = q0 - 56 + 4 * j;
            float4 v = make_float4(0.f, 0.f, 0.f, 0.f);
            if (qf >= 0 && qf <= 2080)
                v = *reinterpret_cast<const float4*>(in_tT + (size_t)(c0 + r) * TPITCH + qf);
            s_in4[r * 104 + j + (j >> 3)] = v;
        }
        __syncthreads();
#pragma unroll 1
        for (int r = 0; r < 16; ++r) {
            const float4* row4 = s_in4 + r * 104;
            const float4* w4 = reinterpret_cast<const float4*>(wbase + (size_t)(c0 + r) * 72);
#pragma unroll
            for (int dy = 0; dy < 3; ++dy) {
                int v0 = lane + 13 * dy;
                int v1 = v0 + 1, v2 = v0 + 2;
                float4 F0 = row4[v0 + (v0 >> 3)];
                float4 F1 = row4[v1 + (v1 >> 3)];
                float4 F2 = row4[v2 + (v2 >> 3)];
                float F[12] = {F0.x, F0.y, F0.z, F0.w, F1.x, F1.y, F1.z, F1.w,
                               F2.x, F2.y, F2.z, F2.w};
#pragma unroll
                for (int dxi = 0; dxi < 3; ++dxi) {
                    int k = dy * 3 + dxi;
                    float4 wa = w4[k * 2], wb = w4[k * 2 + 1];
                    float wv[8] = {wa.x, wa.y, wa.z, wa.w, wb.x, wb.y, wb.z, wb.w};
#pragma unroll
                    for (int jj = 0; jj < 4; ++jj) {
                        float iv = F[jj + dxi + 3];
#pragma unroll
                        for (int c = 0; c < 8; ++c) acc[jj][c] += iv * wv[c];
                    }
                }
            }
        }
        __syncthreads();
    }
    float* part = partial + (size_t)z * P * CMID;
#pragma unroll
    for (int jj = 0; jj < 4; ++jj) {
        int q = q0 + 4 * lane + jj;
        if (q < QP) {
            int hp = q / WP, wp_ = q - hp * WP;
            if (hp >= 1 && hp <= H && wp_ >= 1 && wp_ <= W) {
                int p = (hp - 1) * W + (wp_ - 1);
                float* dst = part + (size_t)p * CMID + cout0 + sub * 8;
                float4* d4 = reinterpret_cast<float4*>(dst);
                d4[0] = make_float4(acc[jj][0], acc[jj][1], acc[jj][2], acc[jj][3]);
                d4[1] = make_float4(acc[jj][4], acc[jj][5], acc[jj][6], acc[jj][7]);
            }
        }
    }
}

// sum partials + bias + relu -> mid [P][CMID]
__global__ __launch_bounds__(256) void k_reduce(const float* __restrict__ partial,
                                                const float* __restrict__ bias,
                                                float* __restrict__ mid) {
    int p = blockIdx.x, c = threadIdx.x;
    float s = bias[c];
    for (int ks = 0; ks < KS; ++ks) s += partial[(size_t)ks * P * CMID + (size_t)p * CMID + c];
    mid[(size_t)p * CMID + c] = fmaxf(s, 0.f);
}

// 1x1 heads + softmax + anchors + loc2bbox + clip. 16 positions per block (4 reps).
__global__ __launch_bounds__(256) void k_heads(const float* __restrict__ mid,
                                               const float* __restrict__ score_w,
                                               const float* __restrict__ score_b,
                                               const float* __restrict__ loc_w,
                                               const float* __restrict__ loc_b,
                                               float* __restrict__ score_out,
                                               float* __restrict__ loc_out,
                                               float* __restrict__ anch_out,
                                               float* __restrict__ fg,
                                               float* __restrict__ boxes) {
    __shared__ float wl[256][56];
    __shared__ float bias[56];
    __shared__ float dots[4][64];
    int t = threadIdx.x;
    for (int idx = t; idx < 18 * 256; idx += 256) {
        int c = idx >> 8, i = idx & 255;
        wl[i][c] = score_w[idx];
    }
    for (int idx = t; idx < 36 * 256; idx += 256) {
        int c = idx >> 8, i = idx & 255;
        wl[i][18 + c] = loc_w[idx];
    }
    if (t < 18) bias[t] = score_b[t];
    else if (t < 54) bias[t] = loc_b[t - 18];
    __syncthreads();

    int pl = t >> 6, c = t & 63;
    for (int rep = 0; rep < 4; ++rep) {
        int p = blockIdx.x * 16 + rep * 4 + pl;
        if (c < 54 && p < P) {
            float d = bias[c];
            const float4* mp = reinterpret_cast<const float4*>(mid + (size_t)p * CMID);
            for (int i4 = 0; i4 < 64; ++i4) {
                float4 m4 = mp[i4];
                int i = i4 * 4;
                d += m4.x * wl[i][c] + m4.y * wl[i + 1][c] + m4.z * wl[i + 2][c] + m4.w * wl[i + 3][c];
            }
            dots[pl][c] = d;
        }
        __syncthreads();
        if (c < NA && p < P) {
            int a = c;
            int idx = p * NA + a;
            float l0 = dots[pl][2 * a], l1 = dots[pl][2 * a + 1];
            float mx = fmaxf(l0, l1);
            float e0 = expf(l0 - mx), e1 = expf(l1 - mx);
            float den = e0 + e1;
            float s0 = e0 / den, s1 = e1 / den;
            score_out[(size_t)idx * 2 + 0] = s0;
            score_out[(size_t)idx * 2 + 1] = s1;
            fg[idx] = s1;
            float dx = dots[pl][18 + 4 * a + 0];
            float dy = dots[pl][18 + 4 * a + 1];
            float dw = dots[pl][18 + 4 * a + 2];
            float dh = dots[pl][18 + 4 * a + 3];
            loc_out[(size_t)idx * 4 + 0] = dx;
            loc_out[(size_t)idx * 4 + 1] = dy;
            loc_out[(size_t)idx * 4 + 2] = dw;
            loc_out[(size_t)idx * 4 + 3] = dh;
            int hh = p / W, ww = p % W;
            const double scales[3] = {8.0, 16.0, 32.0};
            const double ratios[3] = {0.5, 1.0, 2.0};
            double s = scales[a / 3], r = ratios[a % 3];
            double wb2 = 16.0 * s * sqrt(r);
            double hb = wb2 / r;
            double xmin = 8.0 - wb2 / 2.0, ymin = 8.0 - hb / 2.0;
            float b0 = (float)xmin, b1 = (float)ymin;
            float b2 = (float)(xmin + wb2), b3 = (float)(ymin + hb);
            float gx = (float)(ww * 16), gy = (float)(hh * 16);
            float a0 = gx + b0, a1 = gy + b1, a2 = gx + b2, a3 = gy + b3;
            anch_out[(size_t)idx * 4 + 0] = a0;
            anch_out[(size_t)idx * 4 + 1] = a1;
            anch_out[(size_t)idx * 4 + 2] = a2;
            anch_out[(size_t)idx * 4 + 3] = a3;
            float aw = a2 - a0, ah = a3 - a1;
            float cx = a0 + 0.5f * aw, cy = a1 + 0.5f * ah;
            float ncx = dx * aw + cx, ncy = dy * ah + cy;
            float nw = expf(dw) * aw, nh = expf(dh) * ah;
            float x1 = ncx - 0.5f * nw, y1 = ncy - 0.5f * nh;
            float x2 = ncx + 0.5f * nw, y2 = ncy + 0.5f * nh;
            x1 = fminf(fmaxf(x1, 0.f), (float)(W * 16));
            x2 = fminf(fmaxf(x2, 0.f), (float)(W * 16));
            y1 = fminf(fmaxf(y1, 0.f), (float)(H * 16));
            y2 = fminf(fmaxf(y2, 0.f), (float)(H * 16));
            float4* bp = reinterpret_cast<float4*>(boxes);
            bp[idx] = make_float4(x1, y1, x2, y2);
        }
        __syncthreads();
    }
}

// partial stable-descending rank counts over a j-slice. grid (67, 8)
static constexpr int JSL = 2144;  // slice size (mult of 4)
__global__ __launch_bounds__(256) void k_rank_part(const float* __restrict__ fg,
                                                   int* __restrict__ cntb) {
    __shared__ float4 tile[256];
    int t = threadIdx.x;
    int i = blockIdx.x * 256 + t;
    int j0 = blockIdx.y * JSL;
    int j1 = min(NBOX, j0 + JSL);
    float my = (i < NBOX) ? fg[i] : 0.f;
    int cnt = 0;
    for (int base = j0; base < j1; base += 1024) {
        int j = base + t * 4;
        float4 v = make_float4(-3.4e38f, -3.4e38f, -3.4e38f, -3.4e38f);
        if (j + 3 < j1) {
            v = *reinterpret_cast<const float4*>(fg + j);
        } else {
            if (j < j1) v.x = fg[j];
            if (j + 1 < j1) v.y = fg[j + 1];
            if (j + 2 < j1) v.z = fg[j + 2];
            if (j + 3 < j1) v.w = fg[j + 3];
        }
        __syncthreads();
        tile[t] = v;
        __syncthreads();
        if (i < NBOX) {
            for (int u = 0; u < 256; ++u) {
                float4 s = tile[u];
                int jb = base + u * 4;
                cnt += (s.x > my) || (s.x == my && jb < i);
                cnt += (s.y > my) || (s.y == my && jb + 1 < i);
                cnt += (s.z > my) || (s.z == my && jb + 2 < i);
                cnt += (s.w > my) || (s.w == my && jb + 3 < i);
            }
        }
    }
    if (i < NBOX && cnt) atomicAdd(&cntb[i], cnt);
}

// scatter boxes to sorted order using rank counts
__global__ __launch_bounds__(256) void k_scatter(const int* __restrict__ cntb,
                                                 const float* __restrict__ boxes,
                                                 float* __restrict__ sboxes,
                                                 float* __restrict__ sarea) {
    int i = blockIdx.x * 256 + threadIdx.x;
    if (i >= NBOX) return;
    int c = cntb[i];
    float4 b = reinterpret_cast<const float4*>(boxes)[i];
    reinterpret_cast<float4*>(sboxes)[c] = b;
    sarea[c] = (b.z - b.x) * (b.w - b.y);
}

// NMS pair bitmask, row-major: mask[i][w] bit jb = (IoU(i, w*64+jb) > T && j > i)
__global__ __launch_bounds__(256) void k_maskfill(const float* __restrict__ sboxes,
                                                  const float* __restrict__ sarea,
                                                  U64* __restrict__ mask) {
    int w = blockIdx.y;
    int i0 = blockIdx.x * 256;
    if (w < (i0 >> 6)) return;
    __shared__ float4 sb[64];
    __shared__ float sa[64];
    int t = threadIdx.x;
    if (t < 64) {
        int j = w * 64 + t;
        if (j < NBOX) {
            sb[t] = reinterpret_cast<const float4*>(sboxes)[j];
            sa[t] = sarea[j];
        } else {
            sb[t] = make_float4(0.f, 0.f, 0.f, 0.f);
            sa[t] = 0.f;
        }
    }
    __syncthreads();
    int i = i0 + t;
    if (i >= NBOX || w < (i >> 6)) return;
    float4 bi = reinterpret_cast<const float4*>(sboxes)[i];
    float ai = sarea[i];
    U64 word = 0;
#pragma unroll 4
    for (int jb = 0; jb < 64; ++jb) {
        int j = w * 64 + jb;
        float4 bj = sb[jb];
        float xx1 = fmaxf(bi.x, bj.x), yy1 = fmaxf(bi.y, bj.y);
        float xx2 = fminf(bi.z, bj.z), yy2 = fminf(bi.w, bj.w);
        float inter = fmaxf(xx2 - xx1, 0.f) * fmaxf(yy2 - yy1, 0.f);
        float iou = inter / (ai + sa[jb] - inter);
        word |= ((U64)((iou > NMS_T) && (j > i))) << jb;
    }
    mask[(size_t)i * MSTRIDE + w] = word;
}

// exact greedy sweep v4: wave-specialized, depth-2 prefetch, row-parallel far-OR.
// Wave0: resolve + outputs + near-OR (register butterfly) + refill prefetch.
// Waves1-3: previous group's kept ROWS swept along w (coalesced 512B loads).
__global__ __launch_bounds__(256) void k_sweep(const U64* __restrict__ mask,
                                               const float* __restrict__ sboxes,
                                               float* __restrict__ rois_out,
                                               float* __restrict__ keep_out) {
    __shared__ U64 rem[NW];
    __shared__ int klbuf[2][64];
    __shared__ int kn[2];
    __shared__ unsigned base_s;
    int t = threadIdx.x;
    for (int u = t; u < NW; u += 256) rem[u] = 0;
    if (t == 0) { base_s = 0; kn[0] = 0; kn[1] = 0; }

    // prologue prefetch: diag+near for g=0 (A regs) and g=1 (B regs)
    U64 dA = 0, nA = 0, dB = 0, nB = 0;
    if (t < 64) {
        dA = mask[(size_t)t * MSTRIDE + 0];
        nA = mask[(size_t)t * MSTRIDE + 1];
        int r1 = 64 + t;
        dB = mask[(size_t)r1 * MSTRIDE + 1];
        nB = mask[(size_t)r1 * MSTRIDE + 2];
    }
    __syncthreads();

    auto body = [&](int g, U64& dR, U64& nR) {
        if (t < 64) {
            // ---- wave 0: resolve current group from registers ----
            int nv = min(64, NBOX - g * 64);
            U64 vmask = (nv == 64) ? ~0ull : ((1ull << nv) - 1);
            U64 notsup = ~rem[g] & vmask;
            U64 kept = 0;
            while (notsup) {
                int i = (int)__builtin_ctzll(notsup);
                kept |= (1ull << i);
                U64 wi = rdlane64(dR, i);
                notsup &= ~(wi | (1ull << i));
            }
            int nk = __popcll(kept);
            bool mine = (kept >> t) & 1ull;

            // near-OR into rem[g+1] from prefetched registers (butterfly)
            U64 val = mine ? nR : 0;
#pragma unroll
            for (int s = 1; s < 64; s <<= 1) val |= (U64)__shfl_xor((unsigned long long)val, s, 64);
            if (t == 0 && g + 1 < NW && val) atomicOr(&rem[g + 1], val);

            // refill prefetch registers for group g+2
            if (g + 2 < NW) {
                int row = (g + 2) * 64 + t;
                dR = (row < NBOX) ? mask[(size_t)row * MSTRIDE + (g + 2)] : 0;
                nR = (row < NBOX && g + 3 < NW) ? mask[(size_t)row * MSTRIDE + (g + 3)] : 0;
            }

            // outputs + klist publish
            unsigned base = base_s;
            if (mine) {
                unsigned pre = (unsigned)__popcll(kept & ((1ull << t) - 1));
                unsigned dst = base + pre;
                float4 bb = reinterpret_cast<const float4*>(sboxes)[g * 64 + t];
                reinterpret_cast<float4*>(rois_out)[dst] = bb;
                keep_out[dst] = 1.0f;
                klbuf[g & 1][pre] = t;
            }
            if (t == 0) {
                kn[g & 1] = nk;
                base_s = base + (unsigned)nk;
            }
        } else if (g >= 1) {
            // ---- waves 1-3: sweep previous group's kept rows along w (coalesced) ----
            int pb = (g - 1) & 1;
            int nkp = kn[pb];
            int wv = (t >> 6) - 1;   // 0..2
            int lane = t & 63;
            for (int j = wv; j < nkp; j += 3) {
                int row = (g - 1) * 64 + klbuf[pb][j];
                const U64* rp = mask + (size_t)row * MSTRIDE;
                for (int w = g + 1 + lane; w < NW; w += 64) {
                    U64 v = rp[w];
                    if (v) atomicOr(&rem[w], v);
                }
            }
        }
        __syncthreads();
    };

    for (int gg = 0; gg < NW; gg += 2) {
        body(gg, dA, nA);
        body(gg + 1, dB, nB);
    }
}

// ---------------- launch ----------------
extern "C" void kernel_launch(void* const* d_in, const int* in_sizes, int n_in,
                              void* d_out, int out_size, void* d_ws, size_t ws_size,
                              hipStream_t stream) {
    const float* fm      = (const float*)d_in[0];
    const float* conv_w  = (const float*)d_in[2];
    const float* conv_b  = (const float*)d_in[3];
    const float* score_w = (const float*)d_in[4];
    const float* score_b = (const float*)d_in[5];
    const float* loc_w   = (const float*)d_in[6];
    const float* loc_b   = (const float*)d_in[7];

    float* out = (float*)d_out;
    float* rois_out  = out;
    float* keep_out  = out + NBOX * 4;
    float* anch_out  = out + NBOX * 5;
    float* loc_out   = out + NBOX * 9;
    float* score_out = out + NBOX * 13;

    if (ws_size < WS_NEED) {
        k_sentinel<<<(out_size + 255) / 256, 256, 0, stream>>>(out, out_size);
        return;
    }

    char* ws = (char*)d_ws;
    float* in_tT   = (float*)(ws + OFF_INT);
    float* w2      = (float*)(ws + OFF_WT);
    float* partial = (float*)(ws + OFF_PART);
    U64*   mask    = (U64*)(ws + OFF_MASK);
    float* mid     = (float*)(ws + OFF_MID);
    float* fg      = (float*)(ws + OFF_FG);
    float* boxes   = (float*)(ws + OFF_BOX);
    float* sboxes  = (float*)(ws + OFF_SBOX);
    float* sarea   = (float*)(ws + OFF_SAREA);
    int*   cntb    = (int*)(ws + OFF_CNT);

    hipMemsetAsync(in_tT, 0, SZ_INT, stream);
    k_in_t<<<(CIN * H * W + 255) / 256, 256, 0, stream>>>(fm, in_tT);
    k_w_t<<<(CMID * CIN * 9 + 255) / 256, 256, 0, stream>>>(conv_w, w2);
    k_conv<<<504, 256, 0, stream>>>(in_tT, w2, partial);
    k_reduce<<<P, 256, 0, stream>>>(partial, conv_b, mid);
    k_heads<<<(P + 15) / 16, 256, 0, stream>>>(mid, score_w, score_b, loc_w, loc_b,
                                               score_out, loc_out, anch_out, fg, boxes);
    hipMemsetAsync(cntb, 0, NBOX * 4, stream);
    k_rank_part<<<dim3((NBOX + 255) / 256, 8), 256, 0, stream>>>(fg, cntb);
    k_scatter<<<(NBOX + 255) / 256, 256, 0, stream>>>(cntb, boxes, sboxes, sarea);
    hipMemsetAsync(rois_out, 0, (size_t)NBOX * 5 * 4, stream);  // rois_out + keep
    k_maskfill<<<dim3((NBOX + 255) / 256, NW), 256, 0, stream>>>(sboxes, sarea, mask);
    k_sweep<<<1, 256, 0, stream>>>(mask, sboxes, rois_out, keep_out);
}

// Round 8
// 912.851 us; speedup vs baseline: 1.0301x; 1.0301x over previous
//
#include <hip/hip_runtime.h>
#include <cstdint>

#define U64 unsigned long long

static constexpr int H = 38, W = 50, P = 1900;        // feature map
static constexpr int CIN = 2048, CMID = 256;
static constexpr int NA = 9, NBOX = 17100;            // 1900*9
static constexpr int HP = 40, WP = 52, QP = HP * WP;  // padded positions (2080)
static constexpr int TPITCH = 2084;                   // in_tT row pitch (floats), mult of 4
static constexpr int KS = 7;                          // split-K over cin
static constexpr int NW = 268;                        // u64 words covering NBOX bits
static constexpr int MSTRIDE = 272;                   // mask row stride (words)
static constexpr float NMS_T = 0.5f;
static constexpr int QTILE = 256;

// ---------------- ws layout (bytes) ----------------
static constexpr size_t SZ_INT  = (size_t)CIN * TPITCH * 4;   // 17,072,128
static constexpr size_t SZ_WT   = (size_t)9 * CIN * CMID * 4; // 18,874,368
static constexpr size_t SZ_PART = (size_t)KS * P * CMID * 4;  // 13,619,200
static constexpr size_t OFF_INT  = 0;
static constexpr size_t OFF_WT   = OFF_INT + SZ_INT;
static constexpr size_t OFF_PART = OFF_WT + SZ_WT;
static constexpr size_t REGA     = OFF_PART + SZ_PART;        // 49,565,696
// region A overlay (dead after k_reduce): mask + coalesced diag/near bands
static constexpr size_t OFF_MASK = 0;                          // mask [NBOX][MSTRIDE] (37.2 MB)
static constexpr size_t SZ_MASK  = (size_t)NBOX * MSTRIDE * 8; // 37,209,600
static constexpr size_t OFF_DIAG = SZ_MASK;                    // diagA [NBOX] u64 (136.8 KB)
static constexpr size_t OFF_NEAR = OFF_DIAG + 136832;          // near1A [NBOX] u64
static constexpr size_t OFF_MID  = REGA;
static constexpr size_t OFF_FG   = OFF_MID + 1945600;
static constexpr size_t OFF_BOX  = OFF_FG + 68608;
static constexpr size_t OFF_SBOX = OFF_BOX + 273664;
static constexpr size_t OFF_SAREA= OFF_SBOX + 273664;
static constexpr size_t OFF_CNT  = OFF_SAREA + 68608;
static constexpr size_t WS_NEED  = OFF_CNT + 68608;            // ~52.26 MB (unchanged)

__device__ __forceinline__ U64 rdlane64(U64 v, int l) {
    unsigned lo = (unsigned)__builtin_amdgcn_readlane((int)(unsigned)(v & 0xffffffffull), l);
    unsigned hi = (unsigned)__builtin_amdgcn_readlane((int)(unsigned)(v >> 32), l);
    return ((U64)hi << 32) | (U64)lo;
}

// ---------------- kernels ----------------

__global__ __launch_bounds__(256) void k_sentinel(float* out, int n) {
    int i = blockIdx.x * 256 + threadIdx.x;
    if (i < n) out[i] = 1.2345678e8f;
}

// feature_map [CIN][H][W] -> in_tT [CIN][TPITCH] (padded image rows; memset first)
__global__ __launch_bounds__(256) void k_in_t(const float* __restrict__ fm, float* __restrict__ in_tT) {
    int idx = blockIdx.x * 256 + threadIdx.x;
    if (idx >= CIN * (H * W)) return;
    int ci = idx / (H * W), hw = idx - ci * (H * W);
    int h = hw / W, w = hw - h * W;
    in_tT[(size_t)ci * TPITCH + (h + 1) * WP + 1 + w] = fm[idx];
}

// conv_w [CMID][CIN][3][3] -> w2 [y(8)][sub(4)][ci(2048)][k(9)][c(8)]
__global__ __launch_bounds__(256) void k_w_t(const float* __restrict__ cw, float* __restrict__ w2) {
    int idx = blockIdx.x * 256 + threadIdx.x;
    if (idx >= CMID * CIN * 9) return;
    int co = idx / (CIN * 9);
    int rem = idx - co * (CIN * 9);
    int ci = rem / 9, k = rem - ci * 9;
    w2[((size_t)(co >> 3) * CIN + ci) * 72 + k * 8 + (co & 7)] = cw[idx];
}

// 3x3 conv, split-K. grid 504 = 9 qtiles x 8 cout-groups x 7 z (XCD-swizzled).
__global__ __launch_bounds__(256, 2) void k_conv(const float* __restrict__ in_tT,
                                                 const float* __restrict__ w2,
                                                 float* __restrict__ partial) {
    __shared__ float4 s_in4[16 * 104];   // 16 ci x 104 skewed quads (26.6 KB)
    int t = threadIdx.x;
    int lane = t & 63;
    int sub = __builtin_amdgcn_readfirstlane(t >> 6);   // wave-uniform SGPR

    int raw = blockIdx.x;
    int xcd = raw & 7, i0 = raw >> 3;
    int L = xcd * 63 + i0;          // 504 = 8*63, bijective
    int z = L / 72;
    int r0 = L - z * 72;
    int bx = r0 % 9, by = r0 / 9;
    int q0 = bx * QTILE;
    int cout0 = by * 32;
    int cin0 = (z <= 1) ? 304 * z : 608 + 288 * (z - 2);   // 304,304,288x5
    int cin1 = cin0 + ((z <= 1) ? 304 : 288);

    float acc[4][8];
#pragma unroll
    for (int j = 0; j < 4; ++j)
#pragma unroll
        for (int c = 0; c < 8; ++c) acc[j][c] = 0.f;

    const float* wbase = w2 + (size_t)(by * 4 + sub) * CIN * 72;

    for (int c0 = cin0; c0 < cin1; c0 += 16) {
        for (int idx = t; idx < 16 * 92; idx += 256) {
            int r = idx / 92, j = idx - r * 92;
            int qf = q0 - 56 + 4 * j;
            float4 v = make_float4(0.f, 0.f, 0.f, 0.f);
            if (qf >= 0 && qf <= 2080)
                v = *reinterpret_cast<const float4*>(in_tT + (size_t)(c0 + r) * TPITCH + qf);
            s_in4[r * 104 + j + (j >> 3)] = v;
        }
        __syncthreads();
#pragma unroll 1
        for (int r = 0; r < 16; ++r) {
            const float4* row4 = s_in4 + r * 104;
            const float4* w4 = reinterpret_cast<const float4*>(wbase + (size_t)(c0 + r) * 72);
#pragma unroll
            for (int dy = 0; dy < 3; ++dy) {
                int v0 = lane + 13 * dy;
                int v1 = v0 + 1, v2 = v0 + 2;
                float4 F0 = row4[v0 + (v0 >> 3)];
                float4 F1 = row4[v1 + (v1 >> 3)];
                float4 F2 = row4[v2 + (v2 >> 3)];
                float F[12] = {F0.x, F0.y, F0.z, F0.w, F1.x, F1.y, F1.z, F1.w,
                               F2.x, F2.y, F2.z, F2.w};
#pragma unroll
                for (int dxi = 0; dxi < 3; ++dxi) {
                    int k = dy * 3 + dxi;
                    float4 wa = w4[k * 2], wb = w4[k * 2 + 1];
                    float wv[8] = {wa.x, wa.y, wa.z, wa.w, wb.x, wb.y, wb.z, wb.w};
#pragma unroll
                    for (int jj = 0; jj < 4; ++jj) {
                        float iv = F[jj + dxi + 3];
#pragma unroll
                        for (int c = 0; c < 8; ++c) acc[jj][c] += iv * wv[c];
                    }
                }
            }
        }
        __syncthreads();
    }
    float* part = partial + (size_t)z * P * CMID;
#pragma unroll
    for (int jj = 0; jj < 4; ++jj) {
        int q = q0 + 4 * lane + jj;
        if (q < QP) {
            int hp = q / WP, wp_ = q - hp * WP;
            if (hp >= 1 && hp <= H && wp_ >= 1 && wp_ <= W) {
                int p = (hp - 1) * W + (wp_ - 1);
                float* dst = part + (size_t)p * CMID + cout0 + sub * 8;
                float4* d4 = reinterpret_cast<float4*>(dst);
                d4[0] = make_float4(acc[jj][0], acc[jj][1], acc[jj][2], acc[jj][3]);
                d4[1] = make_float4(acc[jj][4], acc[jj][5], acc[jj][6], acc[jj][7]);
            }
        }
    }
}

// sum partials + bias + relu -> mid [P][CMID]
__global__ __launch_bounds__(256) void k_reduce(const float* __restrict__ partial,
                                                const float* __restrict__ bias,
                                                float* __restrict__ mid) {
    int p = blockIdx.x, c = threadIdx.x;
    float s = bias[c];
    for (int ks = 0; ks < KS; ++ks) s += partial[(size_t)ks * P * CMID + (size_t)p * CMID + c];
    mid[(size_t)p * CMID + c] = fmaxf(s, 0.f);
}

// 1x1 heads + softmax + anchors + loc2bbox + clip. 16 positions per block (4 reps).
__global__ __launch_bounds__(256) void k_heads(const float* __restrict__ mid,
                                               const float* __restrict__ score_w,
                                               const float* __restrict__ score_b,
                                               const float* __restrict__ loc_w,
                                               const float* __restrict__ loc_b,
                                               float* __restrict__ score_out,
                                               float* __restrict__ loc_out,
                                               float* __restrict__ anch_out,
                                               float* __restrict__ fg,
                                               float* __restrict__ boxes) {
    __shared__ float wl[256][56];
    __shared__ float bias[56];
    __shared__ float dots[4][64];
    int t = threadIdx.x;
    for (int idx = t; idx < 18 * 256; idx += 256) {
        int c = idx >> 8, i = idx & 255;
        wl[i][c] = score_w[idx];
    }
    for (int idx = t; idx < 36 * 256; idx += 256) {
        int c = idx >> 8, i = idx & 255;
        wl[i][18 + c] = loc_w[idx];
    }
    if (t < 18) bias[t] = score_b[t];
    else if (t < 54) bias[t] = loc_b[t - 18];
    __syncthreads();

    int pl = t >> 6, c = t & 63;
    for (int rep = 0; rep < 4; ++rep) {
        int p = blockIdx.x * 16 + rep * 4 + pl;
        if (c < 54 && p < P) {
            float d = bias[c];
            const float4* mp = reinterpret_cast<const float4*>(mid + (size_t)p * CMID);
            for (int i4 = 0; i4 < 64; ++i4) {
                float4 m4 = mp[i4];
                int i = i4 * 4;
                d += m4.x * wl[i][c] + m4.y * wl[i + 1][c] + m4.z * wl[i + 2][c] + m4.w * wl[i + 3][c];
            }
            dots[pl][c] = d;
        }
        __syncthreads();
        if (c < NA && p < P) {
            int a = c;
            int idx = p * NA + a;
            float l0 = dots[pl][2 * a], l1 = dots[pl][2 * a + 1];
            float mx = fmaxf(l0, l1);
            float e0 = expf(l0 - mx), e1 = expf(l1 - mx);
            float den = e0 + e1;
            float s0 = e0 / den, s1 = e1 / den;
            score_out[(size_t)idx * 2 + 0] = s0;
            score_out[(size_t)idx * 2 + 1] = s1;
            fg[idx] = s1;
            float dx = dots[pl][18 + 4 * a + 0];
            float dy = dots[pl][18 + 4 * a + 1];
            float dw = dots[pl][18 + 4 * a + 2];
            float dh = dots[pl][18 + 4 * a + 3];
            loc_out[(size_t)idx * 4 + 0] = dx;
            loc_out[(size_t)idx * 4 + 1] = dy;
            loc_out[(size_t)idx * 4 + 2] = dw;
            loc_out[(size_t)idx * 4 + 3] = dh;
            int hh = p / W, ww = p % W;
            const double scales[3] = {8.0, 16.0, 32.0};
            const double ratios[3] = {0.5, 1.0, 2.0};
            double s = scales[a / 3], r = ratios[a % 3];
            double wb2 = 16.0 * s * sqrt(r);
            double hb = wb2 / r;
            double xmin = 8.0 - wb2 / 2.0, ymin = 8.0 - hb / 2.0;
            float b0 = (float)xmin, b1 = (float)ymin;
            float b2 = (float)(xmin + wb2), b3 = (float)(ymin + hb);
            float gx = (float)(ww * 16), gy = (float)(hh * 16);
            float a0 = gx + b0, a1 = gy + b1, a2 = gx + b2, a3 = gy + b3;
            anch_out[(size_t)idx * 4 + 0] = a0;
            anch_out[(size_t)idx * 4 + 1] = a1;
            anch_out[(size_t)idx * 4 + 2] = a2;
            anch_out[(size_t)idx * 4 + 3] = a3;
            float aw = a2 - a0, ah = a3 - a1;
            float cx = a0 + 0.5f * aw, cy = a1 + 0.5f * ah;
            float ncx = dx * aw + cx, ncy = dy * ah + cy;
            float nw = expf(dw) * aw, nh = expf(dh) * ah;
            float x1 = ncx - 0.5f * nw, y1 = ncy - 0.5f * nh;
            float x2 = ncx + 0.5f * nw, y2 = ncy + 0.5f * nh;
            x1 = fminf(fmaxf(x1, 0.f), (float)(W * 16));
            x2 = fminf(fmaxf(x2, 0.f), (float)(W * 16));
            y1 = fminf(fmaxf(y1, 0.f), (float)(H * 16));
            y2 = fminf(fmaxf(y2, 0.f), (float)(H * 16));
            float4* bp = reinterpret_cast<float4*>(boxes);
            bp[idx] = make_float4(x1, y1, x2, y2);
        }
        __syncthreads();
    }
}

// partial stable-descending rank counts over a j-slice. grid (67, 8)
static constexpr int JSL = 2144;  // slice size (mult of 4)
__global__ __launch_bounds__(256) void k_rank_part(const float* __restrict__ fg,
                                                   int* __restrict__ cntb) {
    __shared__ float4 tile[256];
    int t = threadIdx.x;
    int i = blockIdx.x * 256 + t;
    int j0 = blockIdx.y * JSL;
    int j1 = min(NBOX, j0 + JSL);
    float my = (i < NBOX) ? fg[i] : 0.f;
    int cnt = 0;
    for (int base = j0; base < j1; base += 1024) {
        int j = base + t * 4;
        float4 v = make_float4(-3.4e38f, -3.4e38f, -3.4e38f, -3.4e38f);
        if (j + 3 < j1) {
            v = *reinterpret_cast<const float4*>(fg + j);
        } else {
            if (j < j1) v.x = fg[j];
            if (j + 1 < j1) v.y = fg[j + 1];
            if (j + 2 < j1) v.z = fg[j + 2];
            if (j + 3 < j1) v.w = fg[j + 3];
        }
        __syncthreads();
        tile[t] = v;
        __syncthreads();
        if (i < NBOX) {
            for (int u = 0; u < 256; ++u) {
                float4 s = tile[u];
                int jb = base + u * 4;
                cnt += (s.x > my) || (s.x == my && jb < i);
                cnt += (s.y > my) || (s.y == my && jb + 1 < i);
                cnt += (s.z > my) || (s.z == my && jb + 2 < i);
                cnt += (s.w > my) || (s.w == my && jb + 3 < i);
            }
        }
    }
    if (i < NBOX && cnt) atomicAdd(&cntb[i], cnt);
}

// scatter boxes to sorted order using rank counts
__global__ __launch_bounds__(256) void k_scatter(const int* __restrict__ cntb,
                                                 const float* __restrict__ boxes,
                                                 float* __restrict__ sboxes,
                                                 float* __restrict__ sarea) {
    int i = blockIdx.x * 256 + threadIdx.x;
    if (i >= NBOX) return;
    int c = cntb[i];
    float4 b = reinterpret_cast<const float4*>(boxes)[i];
    reinterpret_cast<float4*>(sboxes)[c] = b;
    sarea[c] = (b.z - b.x) * (b.w - b.y);
}

// NMS pair bitmask, row-major + coalesced diag/near bands.
__global__ __launch_bounds__(256) void k_maskfill(const float* __restrict__ sboxes,
                                                  const float* __restrict__ sarea,
                                                  U64* __restrict__ mask,
                                                  U64* __restrict__ diagA,
                                                  U64* __restrict__ near1A) {
    int w = blockIdx.y;
    int i0 = blockIdx.x * 256;
    if (w < (i0 >> 6)) return;
    __shared__ float4 sb[64];
    __shared__ float sa[64];
    int t = threadIdx.x;
    if (t < 64) {
        int j = w * 64 + t;
        if (j < NBOX) {
            sb[t] = reinterpret_cast<const float4*>(sboxes)[j];
            sa[t] = sarea[j];
        } else {
            sb[t] = make_float4(0.f, 0.f, 0.f, 0.f);
            sa[t] = 0.f;
        }
    }
    __syncthreads();
    int i = i0 + t;
    if (i >= NBOX || w < (i >> 6)) return;
    float4 bi = reinterpret_cast<const float4*>(sboxes)[i];
    float ai = sarea[i];
    U64 word = 0;
#pragma unroll 4
    for (int jb = 0; jb < 64; ++jb) {
        int j = w * 64 + jb;
        float4 bj = sb[jb];
        float xx1 = fmaxf(bi.x, bj.x), yy1 = fmaxf(bi.y, bj.y);
        float xx2 = fminf(bi.z, bj.z), yy2 = fminf(bi.w, bj.w);
        float inter = fmaxf(xx2 - xx1, 0.f) * fmaxf(yy2 - yy1, 0.f);
        float iou = inter / (ai + sa[jb] - inter);
        word |= ((U64)((iou > NMS_T) && (j > i))) << jb;
    }
    mask[(size_t)i * MSTRIDE + w] = word;
    int gi = i >> 6;
    if (w == gi) diagA[i] = word;
    else if (w == gi + 1) near1A[i] = word;
}

// exact greedy sweep v5: coalesced band prefetch (depth-2), in-resolve near
// accumulation (no butterfly), row-parallel far-OR in waves 1-3.
__global__ __launch_bounds__(256) void k_sweep(const U64* __restrict__ mask,
                                               const U64* __restrict__ diagA,
                                               const U64* __restrict__ near1A,
                                               const float* __restrict__ sboxes,
                                               float* __restrict__ rois_out,
                                               float* __restrict__ keep_out) {
    __shared__ U64 rem[NW];
    __shared__ int klbuf[2][64];
    __shared__ int kn[2];
    __shared__ unsigned base_s;
    int t = threadIdx.x;
    for (int u = t; u < NW; u += 256) rem[u] = 0;
    if (t == 0) { base_s = 0; kn[0] = 0; kn[1] = 0; }

    // prologue prefetch: bands for group 0 (A regs) and group 1 (B regs), coalesced
    U64 dA = 0, nA = 0, dB = 0, nB = 0;
    if (t < 64) {
        dA = diagA[t];       nA = near1A[t];
        dB = diagA[64 + t];  nB = near1A[64 + t];
    }
    __syncthreads();

    auto body = [&](int g, U64& dR, U64& nR) {
        if (t < 64) {
            // issue refill for group g+2 FIRST (coalesced 512B; hides under resolve)
            U64 dNew = 0, nNew = 0;
            if (g + 2 < NW) {
                int row = (g + 2) * 64 + t;
                if (row < NBOX) { dNew = diagA[row]; nNew = near1A[row]; }
            }

            // ---- wave 0: resolve current group; accumulate near-OR in-loop ----
            int nv = min(64, NBOX - g * 64);
            U64 vmask = (nv == 64) ? ~0ull : ((1ull << nv) - 1);
            U64 notsup = ~rem[g] & vmask;
            U64 kept = 0, val = 0;
            while (notsup) {
                int i = (int)__builtin_ctzll(notsup);
                kept |= (1ull << i);
                U64 wi = rdlane64(dR, i);
                val |= rdlane64(nR, i);
                notsup &= ~(wi | (1ull << i));
            }
            int nk = __popcll(kept);
            bool mine = (kept >> t) & 1ull;

            // outputs + klist publish
            unsigned base = base_s;
            if (mine) {
                unsigned pre = (unsigned)__popcll(kept & ((1ull << t) - 1));
                unsigned dst = base + pre;
                float4 bb = reinterpret_cast<const float4*>(sboxes)[g * 64 + t];
                reinterpret_cast<float4*>(rois_out)[dst] = bb;
                keep_out[dst] = 1.0f;
                klbuf[g & 1][pre] = t;
            }
            if (t == 0) {
                kn[g & 1] = nk;
                base_s = base + (unsigned)nk;
                if (g + 1 < NW && val) atomicOr(&rem[g + 1], val);
            }
            dR = dNew; nR = nNew;
        } else if (g >= 1) {
            // ---- waves 1-3: sweep previous group's kept rows along w (coalesced) ----
            int pb = (g - 1) & 1;
            int nkp = kn[pb];
            int wv = (t >> 6) - 1;   // 0..2
            int lane = t & 63;
            for (int j = wv; j < nkp; j += 3) {
                int row = (g - 1) * 64 + klbuf[pb][j];
                const U64* rp = mask + (size_t)row * MSTRIDE;
                for (int w = g + 1 + lane; w < NW; w += 64) {
                    U64 v = rp[w];
                    if (v) atomicOr(&rem[w], v);
                }
            }
        }
        __syncthreads();
    };

    for (int gg = 0; gg < NW; gg += 2) {
        body(gg, dA, nA);
        body(gg + 1, dB, nB);
    }
}

// ---------------- launch ----------------
extern "C" void kernel_launch(void* const* d_in, const int* in_sizes, int n_in,
                              void* d_out, int out_size, void* d_ws, size_t ws_size,
                              hipStream_t stream) {
    const float* fm      = (const float*)d_in[0];
    const float* conv_w  = (const float*)d_in[2];
    const float* conv_b  = (const float*)d_in[3];
    const float* score_w = (const float*)d_in[4];
    const float* score_b = (const float*)d_in[5];
    const float* loc_w   = (const float*)d_in[6];
    const float* loc_b   = (const float*)d_in[7];

    float* out = (float*)d_out;
    float* rois_out  = out;
    float* keep_out  = out + NBOX * 4;
    float* anch_out  = out + NBOX * 5;
    float* loc_out   = out + NBOX * 9;
    float* score_out = out + NBOX * 13;

    if (ws_size < WS_NEED) {
        k_sentinel<<<(out_size + 255) / 256, 256, 0, stream>>>(out, out_size);
        return;
    }

    char* ws = (char*)d_ws;
    float* in_tT   = (float*)(ws + OFF_INT);
    float* w2      = (float*)(ws + OFF_WT);
    float* partial = (float*)(ws + OFF_PART);
    U64*   mask    = (U64*)(ws + OFF_MASK);
    U64*   diagA   = (U64*)(ws + OFF_DIAG);
    U64*   near1A  = (U64*)(ws + OFF_NEAR);
    float* mid     = (float*)(ws + OFF_MID);
    float* fg      = (float*)(ws + OFF_FG);
    float* boxes   = (float*)(ws + OFF_BOX);
    float* sboxes  = (float*)(ws + OFF_SBOX);
    float* sarea   = (float*)(ws + OFF_SAREA);
    int*   cntb    = (int*)(ws + OFF_CNT);

    hipMemsetAsync(in_tT, 0, SZ_INT, stream);
    k_in_t<<<(CIN * H * W + 255) / 256, 256, 0, stream>>>(fm, in_tT);
    k_w_t<<<(CMID * CIN * 9 + 255) / 256, 256, 0, stream>>>(conv_w, w2);
    k_conv<<<504, 256, 0, stream>>>(in_tT, w2, partial);
    k_reduce<<<P, 256, 0, stream>>>(partial, conv_b, mid);
    k_heads<<<(P + 15) / 16, 256, 0, stream>>>(mid, score_w, score_b, loc_w, loc_b,
                                               score_out, loc_out, anch_out, fg, boxes);
    hipMemsetAsync(cntb, 0, NBOX * 4, stream);
    k_rank_part<<<dim3((NBOX + 255) / 256, 8), 256, 0, stream>>>(fg, cntb);
    k_scatter<<<(NBOX + 255) / 256, 256, 0, stream>>>(cntb, boxes, sboxes, sarea);
    hipMemsetAsync(rois_out, 0, (size_t)NBOX * 5 * 4, stream);  // rois_out + keep
    hipMemsetAsync(near1A, 0, NBOX * 8, stream);                // last group has no near word
    k_maskfill<<<dim3((NBOX + 255) / 256, NW), 256, 0, stream>>>(sboxes, sarea, mask, diagA, near1A);
    k_sweep<<<1, 256, 0, stream>>>(mask, diagA, near1A, sboxes, rois_out, keep_out);
}